// Round 3
// baseline (3724.503 us; speedup 1.0000x reference)
//
#include <hip/hip_runtime.h>

// SGLC encoder on MI355X. T=64,B=32,N=64,DIN=H=128, 2 layers, dynamic supports.
// 5 launches: pack weights -> pre(L0) -> rec(L0) -> pre(L1) -> rec(L1).
// pre: x-projections at full-chip parallelism (x@Wg[0:128], x@Wg[256:384],
//      x@Wc[0:128], x@Wc[256:384]) stored bf16 in MFMA C-layout.
// rec: one workgroup per batch chain, h-dependent GEMMs only, acc init from pre.
#define TT 64
#define BB 32
#define NN 64
#define NH 8192

using short8 = __attribute__((ext_vector_type(8))) short;
using f32x16 = __attribute__((ext_vector_type(16))) float;

__device__ __forceinline__ unsigned short f2bf(float f) {
  unsigned int u = __float_as_uint(f);
  u = (u + 0x7FFFu + ((u >> 16) & 1u)) >> 16;
  return (unsigned short)u;
}
__device__ __forceinline__ unsigned int pack2(float a, float b) {
  return (unsigned int)f2bf(a) | ((unsigned int)f2bf(b) << 16);
}
__device__ __forceinline__ uint2 pack4(float a, float b, float c, float d) {
  uint2 r; r.x = pack2(a, b); r.y = pack2(c, d); return r;
}
__device__ __forceinline__ float bf2f(unsigned short s) {
  return __uint_as_float(((unsigned int)s) << 16);
}
__device__ __forceinline__ float sigm(float x) { return 1.0f / (1.0f + __expf(-x)); }
__device__ __forceinline__ float tanh_fast(float x) { return 2.0f / (1.0f + __expf(-2.0f * x)) - 1.0f; }

__device__ __forceinline__ short8 ldsfrag(const unsigned short* p) {
  union { uint2 u2[2]; short8 s; } f;
  f.u2[0] = *(const uint2*)p;
  f.u2[1] = *(const uint2*)(p + 4);
  return f.s;
}
__device__ __forceinline__ short8 ldgfrag(const unsigned short* p) {
  union { uint4 u4; short8 s; } f;
  f.u4 = *(const uint4*)p;
  return f.s;
}
__device__ __forceinline__ void store16(unsigned short* p, const f32x16& v) {
  uint4 q0, q1;
  q0.x = pack2(v[0], v[1]);   q0.y = pack2(v[2], v[3]);
  q0.z = pack2(v[4], v[5]);   q0.w = pack2(v[6], v[7]);
  q1.x = pack2(v[8], v[9]);   q1.y = pack2(v[10], v[11]);
  q1.z = pack2(v[12], v[13]); q1.w = pack2(v[14], v[15]);
  *(uint4*)p = q0; *(uint4*)(p + 8) = q1;
}
__device__ __forceinline__ void addinit(f32x16& a, uint4 c0, uint4 c1) {
  unsigned int u[8] = {c0.x, c0.y, c0.z, c0.w, c1.x, c1.y, c1.z, c1.w};
#pragma unroll
  for (int i = 0; i < 8; ++i) {
    a[2 * i]     += __uint_as_float(u[i] << 16);
    a[2 * i + 1] += __uint_as_float(u[i] & 0xffff0000u);
  }
}

// ===== weight packing: bf16 fragment-major tiles of 4096 ushorts (8 kc x 512).
// Per layer (229376 u): pre region 98304 u (24 tiles), rec region 131072 u (32 tiles).
// pre tiles: 0-7 Wg[0:128], 8-15 Wg[256:384], 16-19 Wc[0:128], 20-23 Wc[256:384]
// rec tiles: 0-7 Wg[128:256], 8-15 Wg[384:512], 16-19 Wc[128:256], 20-23 Wc[384:512],
//            24-27 Wq, 28-31 Wk
__global__ void sglc_pack(const float* __restrict__ Wg0, const float* __restrict__ Wc0,
                          const float* __restrict__ Wq0, const float* __restrict__ Wk0,
                          const float* __restrict__ Wg1, const float* __restrict__ Wc1,
                          const float* __restrict__ Wq1, const float* __restrict__ Wk1,
                          unsigned short* __restrict__ dst) {
  int idx = blockIdx.x * 256 + threadIdx.x;
  if (idx >= 458752) return;
  int layer = idx / 229376;
  int l = idx - layer * 229376;
  const float* Wg = layer ? Wg1 : Wg0;
  const float* Wc = layer ? Wc1 : Wc0;
  const float* Wq = layer ? Wq1 : Wq0;
  const float* Wk = layer ? Wk1 : Wk0;
  int region = (l < 98304) ? 0 : 1;
  int l2 = region ? (l - 98304) : l;
  int tile = l2 >> 12;
  int rem = l2 & 4095;
  int kc = rem >> 9, li = rem & 511;
  int lane = li >> 3, jj = li & 7;
  int krow = kc * 16 + (lane >> 5) * 8 + jj;
  int col32 = lane & 31;
  const float* src; int ld, row0, colbase;
  if (region == 0) {
    if (tile < 8)       { src = Wg; ld = 256; row0 = 0;   colbase = tile * 32; }
    else if (tile < 16) { src = Wg; ld = 256; row0 = 256; colbase = (tile - 8) * 32; }
    else if (tile < 20) { src = Wc; ld = 128; row0 = 0;   colbase = (tile - 16) * 32; }
    else                { src = Wc; ld = 128; row0 = 256; colbase = (tile - 20) * 32; }
  } else {
    if (tile < 8)       { src = Wg; ld = 256; row0 = 128; colbase = tile * 32; }
    else if (tile < 16) { src = Wg; ld = 256; row0 = 384; colbase = (tile - 8) * 32; }
    else if (tile < 20) { src = Wc; ld = 128; row0 = 128; colbase = (tile - 16) * 32; }
    else if (tile < 24) { src = Wc; ld = 128; row0 = 384; colbase = (tile - 20) * 32; }
    else if (tile < 28) { src = Wq; ld = 128; row0 = 0;   colbase = (tile - 24) * 32; }
    else                { src = Wk; ld = 128; row0 = 0;   colbase = (tile - 28) * 32; }
  }
  dst[idx] = f2bf(src[(size_t)(row0 + krow) * ld + colbase + col32]);
}

// ===== precompute: one wave per (t,b), 24 tiles x 2 row-tiles each, bf16 C-layout out.
__global__ void __launch_bounds__(256)
sglc_pre(const float* __restrict__ xbase, const unsigned short* __restrict__ Wpre,
         unsigned short* __restrict__ Pinit) {
  const int gw = blockIdx.x * 4 + (threadIdx.x >> 6);  // 0..2047
  const int lane = threadIdx.x & 63;
  const int n32 = lane & 31, half = lane >> 5;
  const int t = gw >> 5, b = gw & 31;
  const float* xp = xbase + (size_t)(t * BB + b) * NH;
  short8 afr[2][8];
#pragma unroll
  for (int rt = 0; rt < 2; ++rt)
#pragma unroll
    for (int kc = 0; kc < 8; ++kc) {
      const float* s = xp + (size_t)(rt * 32 + n32) * 128 + kc * 16 + half * 8;
      float4 v0 = *(const float4*)s;
      float4 v1 = *(const float4*)(s + 4);
      union { uint2 u[2]; short8 ss; } tmp;
      tmp.u[0] = pack4(v0.x, v0.y, v0.z, v0.w);
      tmp.u[1] = pack4(v1.x, v1.y, v1.z, v1.w);
      afr[rt][kc] = tmp.ss;
    }
  unsigned short* ob = Pinit + ((size_t)(t * BB + b) * 24) * 2048;
  for (int j = 0; j < 24; ++j) {
    f32x16 a0, a1;
#pragma unroll
    for (int z = 0; z < 16; ++z) { a0[z] = 0.0f; a1[z] = 0.0f; }
#pragma unroll
    for (int kc = 0; kc < 8; ++kc) {
      short8 bf = ldgfrag(Wpre + ((j * 8 + kc) << 9) + lane * 8);
      a0 = __builtin_amdgcn_mfma_f32_32x32x16_bf16(afr[0][kc], bf, a0, 0, 0, 0);
      a1 = __builtin_amdgcn_mfma_f32_32x32x16_bf16(afr[1][kc], bf, a1, 0, 0, 0);
    }
    store16(ob + (j * 2 + 0) * 1024 + lane * 16, a0);
    store16(ob + (j * 2 + 1) * 1024 + lane * 16, a1);
  }
}

// ===== recurrent kernel. LDS layout (ushort offsets), total 160768 B:
#define SHB_O  0      // h bf16, 64 x 132
#define SRH_O  8448   // r*h bf16, 64 x 132
#define SSUP_O 16896  // supports bf16, 64 x 68
#define SPT_O  21248  // P2^T / Q2^T bf16, 256 x 68 (17408 u)
#define SQ_O   21248  // q bf16 64x132 (overlays sPT; disjoint in time)
#define SK_O   29696  // k bf16 64x132 (overlays sPT)
#define SS_O   38656  // scores fp32 64 x 66 (8448 u)
#define SHF_O  47104  // h fp32 64 x 130 (16640 u)
#define SU_O   63744  // u fp32 64 x 130 (16640 u)
#define LDS_BYTES 160768

__global__ void __launch_bounds__(1024, 4)
sglc_rec(const float* __restrict__ H0l, const float* __restrict__ Sup0,
         const unsigned short* __restrict__ SupX,
         const float* __restrict__ bg, const float* __restrict__ bc,
         const unsigned short* __restrict__ Wrec, const unsigned short* __restrict__ Pinit,
         unsigned short* __restrict__ SupXout,
         float* __restrict__ OutHl, float* __restrict__ Cur, int layer) {
  extern __shared__ unsigned short sm[];
  unsigned short* sHb  = sm + SHB_O;
  unsigned short* sRH  = sm + SRH_O;
  unsigned short* sSup = sm + SSUP_O;
  unsigned short* sPT  = sm + SPT_O;
  unsigned short* sQ   = sm + SQ_O;
  unsigned short* sK   = sm + SK_O;
  float* sS  = (float*)(sm + SS_O);
  float* sHf = (float*)(sm + SHF_O);
  float* sU  = (float*)(sm + SU_O);

  const int b = blockIdx.x, tid = threadIdx.x;
  const int lane = tid & 63, w = tid >> 6;
  const int n32 = lane & 31, half = lane >> 5, kob = half * 8;

  // resident gates weights: tile w (w0-7: Wg[128:256], w8-15: Wg[384:512])
  short8 wg[8];
#pragma unroll
  for (int kc = 0; kc < 8; ++kc)
    wg[kc] = ldgfrag(Wrec + ((w * 8 + kc) << 9) + lane * 8);

  const float bgv = (w < 8) ? bg[w * 32 + n32] : 0.0f;
  const float bcv = (w >= 4 && w < 8) ? bc[(w - 4) * 32 + n32] : 0.0f;

  // ---- init: h (fp32 + bf16), supports ----
  {
    int r = tid >> 4, c0 = (tid & 15) * 8;
    const float* hp = H0l + (size_t)b * NH + r * 128 + c0;
    float4 v0 = *(const float4*)(hp);
    float4 v1 = *(const float4*)(hp + 4);
    sHf[r * 130 + c0 + 0] = v0.x; sHf[r * 130 + c0 + 1] = v0.y;
    sHf[r * 130 + c0 + 2] = v0.z; sHf[r * 130 + c0 + 3] = v0.w;
    sHf[r * 130 + c0 + 4] = v1.x; sHf[r * 130 + c0 + 5] = v1.y;
    sHf[r * 130 + c0 + 6] = v1.z; sHf[r * 130 + c0 + 7] = v1.w;
    *(uint2*)(sHb + r * 132 + c0)     = pack4(v0.x, v0.y, v0.z, v0.w);
    *(uint2*)(sHb + r * 132 + c0 + 4) = pack4(v1.x, v1.y, v1.z, v1.w);
    if (layer == 0) {
      int cs = (tid & 15) * 4;
      float4 sv = *(const float4*)(Sup0 + (size_t)b * 4096 + r * 64 + cs);
      *(uint2*)(sSup + r * 68 + cs) = pack4(sv.x, sv.y, sv.z, sv.w);
    } else {
      for (int i = tid; i < 4352; i += 1024) sSup[i] = SupX[(size_t)b * 4352 + i];
    }
  }
  __syncthreads();

  for (int t = 0; t < TT; ++t) {
    const size_t pbase = ((size_t)(t * BB + b) * 24) * 2048;

    // ===== seg1: gates h-GEMM (all 16 waves), acc init from Pinit added at end =====
    f32x16 acc0, acc1;
    {
      const unsigned short* pb = Pinit + pbase + (size_t)w * 2048 + lane * 16;
      uint4 c00 = *(const uint4*)(pb);
      uint4 c01 = *(const uint4*)(pb + 8);
      uint4 c10 = *(const uint4*)(pb + 1024);
      uint4 c11 = *(const uint4*)(pb + 1024 + 8);
#pragma unroll
      for (int z = 0; z < 16; ++z) { acc0[z] = 0.0f; acc1[z] = 0.0f; }
#pragma unroll
      for (int kc = 0; kc < 8; ++kc) {
        short8 a0 = ldsfrag(sHb + n32 * 132 + kc * 16 + kob);
        short8 a1 = ldsfrag(sHb + (32 + n32) * 132 + kc * 16 + kob);
        acc0 = __builtin_amdgcn_mfma_f32_32x32x16_bf16(a0, wg[kc], acc0, 0, 0, 0);
        acc1 = __builtin_amdgcn_mfma_f32_32x32x16_bf16(a1, wg[kc], acc1, 0, 0, 0);
      }
      addinit(acc0, c00, c01);
      addinit(acc1, c10, c11);
      if (w >= 8) {  // write P2^T
        unsigned short* pt = sPT + ((w - 8) * 32 + n32) * 68;
#pragma unroll
        for (int tt = 0; tt < 2; ++tt) {
          const f32x16& ac = tt ? acc1 : acc0;
#pragma unroll
          for (int g = 0; g < 4; ++g)
            *(uint2*)(pt + tt * 32 + 8 * g + 4 * half) =
                pack4(ac[4 * g], ac[4 * g + 1], ac[4 * g + 2], ac[4 * g + 3]);
        }
      }
    }
    __syncthreads();  // B1

    // ===== seg2: conv gates (w0-7) -> r (sRH), u (sU); w4-11 stream cand weights =====
    short8 st[8];
    if (w >= 4 && w < 12) {
      const int tile = w + 12;  // 16..23
#pragma unroll
      for (int kc = 0; kc < 8; ++kc)
        st[kc] = ldgfrag(Wrec + ((tile * 8 + kc) << 9) + lane * 8);
    }
    if (w < 8) {
#pragma unroll
      for (int kc2 = 0; kc2 < 4; ++kc2) {
        short8 a0 = ldsfrag(sSup + n32 * 68 + kc2 * 16 + kob);
        short8 a1 = ldsfrag(sSup + (32 + n32) * 68 + kc2 * 16 + kob);
        short8 bf = ldsfrag(sPT + (w * 32 + n32) * 68 + kc2 * 16 + kob);
        acc0 = __builtin_amdgcn_mfma_f32_32x32x16_bf16(a0, bf, acc0, 0, 0, 0);
        acc1 = __builtin_amdgcn_mfma_f32_32x32x16_bf16(a1, bf, acc1, 0, 0, 0);
      }
      const int col = w * 32 + n32;
      if (w < 4) {
#pragma unroll
        for (int tt = 0; tt < 2; ++tt) {
          const f32x16& ac = tt ? acc1 : acc0;
#pragma unroll
          for (int g = 0; g < 4; ++g)
#pragma unroll
            for (int i = 0; i < 4; ++i) {
              int row = tt * 32 + 8 * g + 4 * half + i;
              float rv = sigm(ac[4 * g + i] + bgv);
              sRH[row * 132 + col] = f2bf(rv * sHf[row * 130 + col]);
            }
        }
      } else {
        const int ucol = col - 128;
#pragma unroll
        for (int tt = 0; tt < 2; ++tt) {
          const f32x16& ac = tt ? acc1 : acc0;
#pragma unroll
          for (int g = 0; g < 4; ++g)
#pragma unroll
            for (int i = 0; i < 4; ++i) {
              int row = tt * 32 + 8 * g + 4 * half + i;
              sU[row * 130 + ucol] = sigm(ac[4 * g + i] + bgv);
            }
        }
      }
    }
    __syncthreads();  // B2

    // ===== seg3: cand h-GEMM (w4-11) =====
    f32x16 ca0, ca1;
    if (w >= 4 && w < 12) {
      const unsigned short* pb = Pinit + pbase + (size_t)(w + 12) * 2048 + lane * 16;
      uint4 c00 = *(const uint4*)(pb);
      uint4 c01 = *(const uint4*)(pb + 8);
      uint4 c10 = *(const uint4*)(pb + 1024);
      uint4 c11 = *(const uint4*)(pb + 1024 + 8);
#pragma unroll
      for (int z = 0; z < 16; ++z) { ca0[z] = 0.0f; ca1[z] = 0.0f; }
#pragma unroll
      for (int kc = 0; kc < 8; ++kc) {
        short8 a0 = ldsfrag(sRH + n32 * 132 + kc * 16 + kob);
        short8 a1 = ldsfrag(sRH + (32 + n32) * 132 + kc * 16 + kob);
        ca0 = __builtin_amdgcn_mfma_f32_32x32x16_bf16(a0, st[kc], ca0, 0, 0, 0);
        ca1 = __builtin_amdgcn_mfma_f32_32x32x16_bf16(a1, st[kc], ca1, 0, 0, 0);
      }
      addinit(ca0, c00, c01);
      addinit(ca1, c10, c11);
      if (w >= 8) {  // write Q2^T
        unsigned short* pt = sPT + ((w - 8) * 32 + n32) * 68;
#pragma unroll
        for (int tt = 0; tt < 2; ++tt) {
          const f32x16& ac = tt ? ca1 : ca0;
#pragma unroll
          for (int g = 0; g < 4; ++g)
            *(uint2*)(pt + tt * 32 + 8 * g + 4 * half) =
                pack4(ac[4 * g], ac[4 * g + 1], ac[4 * g + 2], ac[4 * g + 3]);
        }
      }
    }
    __syncthreads();  // B3

    // ===== seg4: conv cand + h update (w4-7); w0-3/w12-15 stream Wq/Wk into st =====
    if (w < 4) {
#pragma unroll
      for (int kc = 0; kc < 8; ++kc)
        st[kc] = ldgfrag(Wrec + (((24 + w) * 8 + kc) << 9) + lane * 8);
    } else if (w >= 12) {
#pragma unroll
      for (int kc = 0; kc < 8; ++kc)
        st[kc] = ldgfrag(Wrec + (((16 + w) * 8 + kc) << 9) + lane * 8);
    }
    if (w >= 4 && w < 8) {
      const int col = (w - 4) * 32 + n32;
#pragma unroll
      for (int kc2 = 0; kc2 < 4; ++kc2) {
        short8 a0 = ldsfrag(sSup + n32 * 68 + kc2 * 16 + kob);
        short8 a1 = ldsfrag(sSup + (32 + n32) * 68 + kc2 * 16 + kob);
        short8 bf = ldsfrag(sPT + ((w - 4) * 32 + n32) * 68 + kc2 * 16 + kob);
        ca0 = __builtin_amdgcn_mfma_f32_32x32x16_bf16(a0, bf, ca0, 0, 0, 0);
        ca1 = __builtin_amdgcn_mfma_f32_32x32x16_bf16(a1, bf, ca1, 0, 0, 0);
      }
      float* curp = Cur + (size_t)(t * BB + b) * NH;
      float* outp = OutHl + (size_t)b * NH;
#pragma unroll
      for (int tt = 0; tt < 2; ++tt) {
        const f32x16& ac = tt ? ca1 : ca0;
#pragma unroll
        for (int g = 0; g < 4; ++g)
#pragma unroll
          for (int i = 0; i < 4; ++i) {
            int row = tt * 32 + 8 * g + 4 * half + i;
            float cv = tanh_fast(ac[4 * g + i] + bcv);
            float uv = sU[row * 130 + col];
            float hn = uv * sHf[row * 130 + col] + (1.0f - uv) * cv;
            sHf[row * 130 + col] = hn;
            sHb[row * 132 + col] = f2bf(hn);
            curp[row * 128 + col] = hn;
            if (t == TT - 1) outp[row * 128 + col] = hn;
          }
      }
    }
    __syncthreads();  // B4

    // ===== seg5: q (w0-3) / k (w12-15) GEMM from h_new =====
    if (w < 4 || w >= 12) {
      f32x16 qa0, qa1;
#pragma unroll
      for (int z = 0; z < 16; ++z) { qa0[z] = 0.0f; qa1[z] = 0.0f; }
#pragma unroll
      for (int kc = 0; kc < 8; ++kc) {
        short8 a0 = ldsfrag(sHb + n32 * 132 + kc * 16 + kob);
        short8 a1 = ldsfrag(sHb + (32 + n32) * 132 + kc * 16 + kob);
        qa0 = __builtin_amdgcn_mfma_f32_32x32x16_bf16(a0, st[kc], qa0, 0, 0, 0);
        qa1 = __builtin_amdgcn_mfma_f32_32x32x16_bf16(a1, st[kc], qa1, 0, 0, 0);
      }
      unsigned short* dq = (w < 4) ? sQ : sK;
      const int col = (w < 4 ? w : w - 12) * 32 + n32;
#pragma unroll
      for (int tt = 0; tt < 2; ++tt) {
        const f32x16& ac = tt ? qa1 : qa0;
#pragma unroll
        for (int g = 0; g < 4; ++g)
#pragma unroll
          for (int i = 0; i < 4; ++i)
            dq[(tt * 32 + 8 * g + 4 * half + i) * 132 + col] = f2bf(ac[4 * g + i]);
      }
    }
    __syncthreads();  // B5

    // ===== seg6: scores = q@k^T, relu (w0-3) =====
    if (w < 4) {
      const int rt = w & 1, ct = w >> 1;
      f32x16 sa;
#pragma unroll
      for (int z = 0; z < 16; ++z) sa[z] = 0.0f;
#pragma unroll
      for (int kc = 0; kc < 8; ++kc) {
        short8 a0 = ldsfrag(sQ + (rt * 32 + n32) * 132 + kc * 16 + kob);
        short8 bf = ldsfrag(sK + (ct * 32 + n32) * 132 + kc * 16 + kob);
        sa = __builtin_amdgcn_mfma_f32_32x32x16_bf16(a0, bf, sa, 0, 0, 0);
      }
#pragma unroll
      for (int g = 0; g < 4; ++g)
#pragma unroll
        for (int i = 0; i < 4; ++i)
          sS[(rt * 32 + 8 * g + 4 * half + i) * 66 + ct * 32 + n32] =
              fmaxf(sa[4 * g + i], 0.0f);
    }
    __syncthreads();  // B6

    // ===== seg7: row softmax -> sSup =====
    {
      int row = tid >> 4, ci = (tid & 15) * 4;
      float2 v01 = *(const float2*)(sS + row * 66 + ci);
      float2 v23 = *(const float2*)(sS + row * 66 + ci + 2);
      float s0 = v01.x, s1 = v01.y, s2 = v23.x, s3 = v23.y;
      float mx = fmaxf(fmaxf(s0, s1), fmaxf(s2, s3));
#pragma unroll
      for (int off = 1; off < 16; off <<= 1) mx = fmaxf(mx, __shfl_xor(mx, off, 16));
      float e0 = __expf(s0 - mx), e1 = __expf(s1 - mx);
      float e2 = __expf(s2 - mx), e3 = __expf(s3 - mx);
      float sum = e0 + e1 + e2 + e3;
#pragma unroll
      for (int off = 1; off < 16; off <<= 1) sum += __shfl_xor(sum, off, 16);
      float inv = 1.0f / sum;
      *(uint2*)(sSup + row * 68 + ci) = pack4(e0 * inv, e1 * inv, e2 * inv, e3 * inv);
    }
    __syncthreads();  // B7
  }  // t

  if (layer == 0) {
    for (int i = tid; i < 4352; i += 1024) SupXout[(size_t)b * 4352 + i] = sSup[i];
  }
}

extern "C" void kernel_launch(void* const* d_in, const int* in_sizes, int n_in,
                              void* d_out, int out_size, void* d_ws, size_t ws_size,
                              hipStream_t stream) {
  const float* Xin  = (const float*)d_in[0];
  const float* H0   = (const float*)d_in[1];
  const float* Sup0 = (const float*)d_in[2];
  const float* Wg0  = (const float*)d_in[3];
  const float* bg0  = (const float*)d_in[4];
  const float* Wc0  = (const float*)d_in[5];
  const float* bc0  = (const float*)d_in[6];
  const float* Wq0  = (const float*)d_in[7];
  const float* Wk0  = (const float*)d_in[8];
  const float* Wg1  = (const float*)d_in[9];
  const float* bg1  = (const float*)d_in[10];
  const float* Wc1  = (const float*)d_in[11];
  const float* bc1  = (const float*)d_in[12];
  const float* Wq1  = (const float*)d_in[13];
  const float* Wk1  = (const float*)d_in[14];

  // ws: weights 458752 u | Pinit 100663296 u | SupX 139264 u  => 202522624 B
  if (ws_size < 202522624ull) return;  // clean failure signal if ws too small
  unsigned short* Wp    = (unsigned short*)d_ws;
  unsigned short* Pinit = Wp + 458752;
  unsigned short* SupX  = Pinit + 100663296;

  float* Out = (float*)d_out;
  float* Cur = Out + 2 * BB * NH;

  hipFuncSetAttribute(reinterpret_cast<const void*>(sglc_rec),
                      hipFuncAttributeMaxDynamicSharedMemorySize, LDS_BYTES);

  hipLaunchKernelGGL(sglc_pack, dim3(1792), dim3(256), 0, stream,
                     Wg0, Wc0, Wq0, Wk0, Wg1, Wc1, Wq1, Wk1, Wp);
  // layer 0
  hipLaunchKernelGGL(sglc_pre, dim3(512), dim3(256), 0, stream, Xin, Wp, Pinit);
  hipLaunchKernelGGL(sglc_rec, dim3(BB), dim3(1024), LDS_BYTES, stream,
                     H0, Sup0, SupX, bg0, bc0, Wp + 98304, Pinit, SupX,
                     Out, Cur, 0);
  // layer 1
  hipLaunchKernelGGL(sglc_pre, dim3(512), dim3(256), 0, stream, Cur, Wp + 229376, Pinit);
  hipLaunchKernelGGL(sglc_rec, dim3(BB), dim3(1024), LDS_BYTES, stream,
                     H0 + BB * NH, Sup0, SupX, bg1, bc1, Wp + 229376 + 98304, Pinit, SupX,
                     Out + BB * NH, Cur, 1);
}